// Round 8
// baseline (439.063 us; speedup 1.0000x reference)
//
#include <hip/hip_runtime.h>
#include <cstdint>
#include <cstddef>

#define T_SEQ 2048
#define B_SZ  8
#define F_DIM 768
#define H_CNT 3
#define DH    256
#define E_ELE (T_SEQ * B_SZ * F_DIM)   // 12582912 elems per activation tensor
#define W_ELE (F_DIM * F_DIM)          // 589824 elems per weight matrix

typedef float floatx4 __attribute__((ext_vector_type(4)));
typedef short bf16x8  __attribute__((ext_vector_type(8)));

// round-half-up f32->bf16 (2 VALU); ties differ from RNE by 1 ulp (noise here)
static __device__ __forceinline__ unsigned short f2bf(float f) {
    union { float f; unsigned int i; } x; x.f = f;
    return (unsigned short)((x.i + 0x8000u) >> 16);
}
// pack two f32 -> u32 of two bf16 (lo=a, hi=b): 2 adds + v_perm
static __device__ __forceinline__ unsigned int pkbf(float a, float b) {
    union { float f; unsigned int i; } xa, xb; xa.f = a; xb.f = b;
    return __builtin_amdgcn_perm(xb.i + 0x8000u, xa.i + 0x8000u, 0x07060302u);
}
// load 8 consecutive fp32, convert to bf16x8 (packed converts)
static __device__ __forceinline__ bf16x8 cvt8(const float* __restrict__ p) {
    const floatx4 a = *(const floatx4*)p;
    const floatx4 b = *(const floatx4*)(p + 4);
    union { unsigned int u[4]; bf16x8 v; } r;
    r.u[0] = pkbf(a[0], a[1]); r.u[1] = pkbf(a[2], a[3]);
    r.u[2] = pkbf(b[0], b[1]); r.u[3] = pkbf(b[2], b[3]);
    return r.v;
}

// async global->LDS, 16B per lane; LDS dest = wave-uniform base + lane*16
#define ASYNC16(g, l) __builtin_amdgcn_global_load_lds( \
    (__attribute__((address_space(1))) void*)(void*)(g), \
    (__attribute__((address_space(3))) void*)(l), 16, 0, 0)

// ---------------------------------------------------------------------------
// Bulk fp32 -> bf16 (grid-stride over 8-elem chunks)
// ---------------------------------------------------------------------------
__global__ __launch_bounds__(256) void cvt_bf16(const float* __restrict__ src,
                                                unsigned short* __restrict__ dst,
                                                int n8)
{
    for (int i = blockIdx.x * 256 + threadIdx.x; i < n8; i += gridDim.x * 256)
        *(bf16x8*)(dst + (size_t)i * 8) = cvt8(src + (size_t)i * 8);
}

// Pack Wq|Wk|Wv|Wo -> bf16 [4*768][768]; pack bq|bk|bv -> fp32[2304].
__global__ __launch_bounds__(256) void cvt_w(
    const float* __restrict__ wq, const float* __restrict__ wk,
    const float* __restrict__ wv, const float* __restrict__ wo,
    const float* __restrict__ bq, const float* __restrict__ bk,
    const float* __restrict__ bv,
    unsigned short* __restrict__ wdst, float* __restrict__ bdst)
{
    const int y = blockIdx.y;
    const float* s = (y == 0) ? wq : (y == 1) ? wk : (y == 2) ? wv : wo;
    const int i = blockIdx.x * 256 + threadIdx.x;
    *(bf16x8*)(wdst + (size_t)y * W_ELE + (size_t)i * 8) = cvt8(s + (size_t)i * 8);
    if (y < 3 && i < F_DIM / 8) {
        const float* bs = (y == 0) ? bq : (y == 1) ? bk : bv;
        *(floatx4*)(bdst + y * F_DIM + i * 8)     = *(const floatx4*)(bs + i * 8);
        *(floatx4*)(bdst + y * F_DIM + i * 8 + 4) = *(const floatx4*)(bs + i * 8 + 4);
    }
}

// ---------------------------------------------------------------------------
// NT GEMM (R6 version, measured best): both operands bf16, staged via
// global_load_lds w16, BK=64. [128][64] granules XOR-swizzled: linear LDS
// dest + inverse-swizzled GLOBAL source (granule (l&7)^(l>>3)) + swizzled
// ds_read granule ((kh*4+q4)^(rr&7)) -> 2-way (free).
// C = (A[M,K] * W[N,K]^T + bias) [* scale].
// CMODE 2: C fp32 row-major.  CMODE 5: fused QKV fragment-layout scatter.
// ---------------------------------------------------------------------------
template<int CMODE>
__global__ __launch_bounds__(256, 3) void gemm_nt(
    const unsigned short* __restrict__ A,
    const unsigned short* __restrict__ W,
    const float* __restrict__ bias,
    void* __restrict__ Cv,
    int M, int N, int K, float qscale)
{
    __shared__ __align__(16) unsigned short As[128 * 64];
    __shared__ __align__(16) unsigned short Bs[128 * 64];

    const int tid  = threadIdx.x;
    const int wave = tid >> 6;
    const int lane = tid & 63;
    const int m0 = blockIdx.y * 128;
    const int n0 = blockIdx.x * 128;
    const int wm = (wave >> 1) * 64;
    const int wn = (wave & 1) * 64;
    const int q4 = lane >> 4;
    const int rr = lane & 15;

    // staging geometry: per ASYNC16 call a wave covers 8 rows x 64 elems.
    const int srow = lane >> 3;                 // row within 8-row group
    const int scol = ((lane & 7) ^ srow) * 8;   // inverse-swizzled src granule

    floatx4 acc[4][4];
#pragma unroll
    for (int i = 0; i < 4; ++i)
#pragma unroll
        for (int j = 0; j < 4; ++j) acc[i][j] = (floatx4)0.0f;

    for (int k0 = 0; k0 < K; k0 += 64) {
        __syncthreads();   // previous iteration's fragment reads complete
#pragma unroll
        for (int c = 0; c < 4; ++c) {
            const int g = wave * 4 + c;         // rowgroup 0..15
            ASYNC16(A + (size_t)(m0 + g * 8 + srow) * K + k0 + scol,
                    (unsigned short*)As + g * 512);
            ASYNC16(W + (size_t)(n0 + g * 8 + srow) * K + k0 + scol,
                    (unsigned short*)Bs + g * 512);
        }
        __syncthreads();   // staging visible (drains vmcnt)

#pragma unroll
        for (int kh = 0; kh < 2; ++kh) {
            bf16x8 af[4], bfv[4];
#pragma unroll
            for (int mt = 0; mt < 4; ++mt) {
                const int row = wm + mt * 16 + rr;
                const int pg = (kh * 4 + q4) ^ (rr & 7);   // swizzled granule
                af[mt] = *(const bf16x8*)&As[row * 64 + pg * 8];
            }
#pragma unroll
            for (int nt = 0; nt < 4; ++nt) {
                const int row = wn + nt * 16 + rr;
                const int pg = (kh * 4 + q4) ^ (rr & 7);
                bfv[nt] = *(const bf16x8*)&Bs[row * 64 + pg * 8];
            }
#pragma unroll
            for (int mt = 0; mt < 4; ++mt)
#pragma unroll
                for (int nt = 0; nt < 4; ++nt)
                    acc[mt][nt] = __builtin_amdgcn_mfma_f32_16x16x32_bf16(af[mt], bfv[nt], acc[mt][nt], 0, 0, 0);
        }
    }

#pragma unroll
    for (int nt = 0; nt < 4; ++nt) {
        const int col = n0 + wn + nt * 16 + rr;
        const float bv = bias[col];
        if (CMODE == 2) {
            float* C = (float*)Cv;
#pragma unroll
            for (int mt = 0; mt < 4; ++mt)
#pragma unroll
                for (int r = 0; r < 4; ++r) {
                    const int row = m0 + wm + mt * 16 + q4 * 4 + r;
                    C[(size_t)row * N + col] = acc[mt][nt][r] + bv;
                }
        } else {  // CMODE 5: fused QKV scatter (16-wide fragment layouts)
            const int mat = col / 768;           // wave-uniform per nt
            const int cl  = col - mat * 768;
            const int h = cl >> 8, d = cl & 255;
            const float sc = (mat == 0) ? qscale : 1.0f;
            unsigned short* base = (unsigned short*)Cv + (size_t)mat * E_ELE;
#pragma unroll
            for (int mt = 0; mt < 4; ++mt) {
#pragma unroll
                for (int r = 0; r < 4; ++r) {
                    const int row = m0 + wm + mt * 16 + q4 * 4 + r;
                    const float v = (acc[mt][nt][r] + bv) * sc;
                    const int t = row >> 3, bb = row & 7;   // row = t*B + b
                    const size_t hb = (size_t)(bb * H_CNT + h) * (T_SEQ * DH);
                    size_t idx;
                    if (mat < 2) {   // Q/K fragment layout
                        const int sblk = t >> 4, rrq = t & 15;
                        const int kc = d >> 5, q4v = (d >> 3) & 3, e = d & 7;
                        idx = hb + (size_t)(((sblk * 8 + kc) * 64 + q4v * 16 + rrq) * 8 + e);
                    } else {         // V fragment layout
                        const int skc = t >> 5, q4v = (t >> 3) & 3, e = t & 7;
                        const int dblk = d >> 4, rrq = d & 15;
                        idx = hb + (size_t)(((skc * 16 + dblk) * 64 + q4v * 16 + rrq) * 8 + e);
                    }
                    base[idx] = f2bf(v);
                }
            }
        }
    }
}

// ---------------------------------------------------------------------------
// Flash attention, covered-drain pipeline: grid (T/64, B*H), 256 threads
// (4 waves), 16 Q rows/wave. K double-buffered (issue K(c+1) at top of chunk
// c -> drained by NEXT chunk's vmcnt(8), covered by a full chunk of compute);
// V single-buffered (issue V(c) at top -> drained by vmcnt(4) after
// QK+softmax, ~1200cyc coverage). Raw s_barriers only -- vmcnt never drains
// to 0 in the loop (K(c+1) always in flight). Outstanding bookkeeping:
// top of chunk c: {K(c)=4} -> +V(c)=4 -> +K(c+1)=4 = 12; vmcnt(8) releases
// K(c); after QK: {V(c),K(c+1)}=8; vmcnt(4) releases V(c).
// ---------------------------------------------------------------------------
__global__ __launch_bounds__(256, 3) void attn_kernel(
    const unsigned short* __restrict__ Qf,
    const unsigned short* __restrict__ Kf,
    const unsigned short* __restrict__ Vf,
    unsigned short* __restrict__ Ob)
{
    __shared__ __align__(16) unsigned short Ks[2][8192];    // dbuf [sblk2][kc8][64][8]
    __shared__ __align__(16) unsigned short Vs[8192];       // [dblk16][64][8]
    __shared__ __align__(16) unsigned short Ps[4][16 * 40]; // per-wave P[q][s], pad 8

    const int tid  = threadIdx.x;
    const int wave = tid >> 6;
    const int lane = tid & 63;
    const int q4 = lane >> 4;
    const int rr = lane & 15;
    const int bh = blockIdx.y;
    const int b  = bh / H_CNT;
    const int h  = bh % H_CNT;
    const size_t hb = (size_t)bh * (T_SEQ * DH);

    // wave's 16 Q rows = fragment tile sb (Q prescaled by 1/8 in the GEMM)
    const int sb = blockIdx.x * 4 + wave;
    bf16x8 qf_[8];
#pragma unroll
    for (int kc = 0; kc < 8; ++kc)
        qf_[kc] = *(const bf16x8*)(Qf + hb + ((size_t)(sb * 8 + kc) * 64 + lane) * 8);

    float m_ = -1e9f, l_ = 0.0f;
    floatx4 oacc[16];
#pragma unroll
    for (int dt = 0; dt < 16; ++dt) oacc[dt] = (floatx4)0.0f;

    const int so = wave * 2048 + lane * 8;   // staging src offset (elems)
    const int sd = wave * 2048;              // staging LDS base (elems)

// issue K-chunk c_ -> Ks[buf_]; 4 ASYNC16/wave (16KB/block). c_ clamped mod 64
// so the final (dead) prefetch stays in bounds and vmcnt counts stay uniform.
#define STGK(buf_, c_) do { \
    const unsigned short* kg_ = Kf + hb + (size_t)((c_) & 63) * 8192; \
    _Pragma("unroll") \
    for (int rnd = 0; rnd < 4; ++rnd) \
        ASYNC16(kg_ + so + rnd * 512, (unsigned short*)Ks[buf_] + sd + rnd * 512); \
} while (0)
#define STGV(c_) do { \
    const unsigned short* vg_ = Vf + hb + (size_t)(c_) * 8192; \
    _Pragma("unroll") \
    for (int rnd = 0; rnd < 4; ++rnd) \
        ASYNC16(vg_ + so + rnd * 512, (unsigned short*)Vs + sd + rnd * 512); \
} while (0)

    STGK(0, 0);   // prologue: K(0) in flight

    for (int c = 0; c < 64; ++c) {
        const int kb = c & 1;
        STGV(c);            // V(c): drained by vmcnt(4) below (covered by QK)
        STGK(kb ^ 1, c + 1);// K(c+1): drained by NEXT chunk's vmcnt(8)
        asm volatile("s_waitcnt vmcnt(8)" ::: "memory");   // K(c) landed (this wave)
        __builtin_amdgcn_s_barrier();                      // all waves: K(c) visible

        // S^T = K Q^T : D[s][q], s-tiles smt=0,1
        floatx4 sacc[2];
        sacc[0] = (floatx4)0.0f; sacc[1] = (floatx4)0.0f;
#pragma unroll
        for (int kc = 0; kc < 8; ++kc) {
            bf16x8 k0 = *(const bf16x8*)&Ks[kb][(kc * 64 + lane) * 8];
            bf16x8 k1 = *(const bf16x8*)&Ks[kb][((8 + kc) * 64 + lane) * 8];
            sacc[0] = __builtin_amdgcn_mfma_f32_16x16x32_bf16(k0, qf_[kc], sacc[0], 0, 0, 0);
            sacc[1] = __builtin_amdgcn_mfma_f32_16x16x32_bf16(k1, qf_[kc], sacc[1], 0, 0, 0);
        }

        // online softmax: lane's q-col = rr; 8 s-values in regs (smt, r)
        float cm = sacc[0][0];
#pragma unroll
        for (int smt = 0; smt < 2; ++smt)
#pragma unroll
            for (int r = 0; r < 4; ++r) cm = fmaxf(cm, sacc[smt][r]);
        cm = fmaxf(cm, __shfl_xor(cm, 16));
        cm = fmaxf(cm, __shfl_xor(cm, 32));
        const float mn = fmaxf(m_, cm);
        const float alpha = __expf(m_ - mn);
        float rs = 0.0f;
#pragma unroll
        for (int smt = 0; smt < 2; ++smt)
#pragma unroll
            for (int r = 0; r < 4; ++r) {
                const float p = __expf(sacc[smt][r] - mn);
                sacc[smt][r] = p; rs += p;
            }
        rs += __shfl_xor(rs, 16);
        rs += __shfl_xor(rs, 32);
        l_ = alpha * l_ + rs;
        const int upd = (mn > m_);
        m_ = mn;

        // P (S^T C-layout) -> per-wave LDS tile P[q][s] (stride 40)
        unsigned short* pw = Ps[wave];
#pragma unroll
        for (int smt = 0; smt < 2; ++smt)
#pragma unroll
            for (int r = 0; r < 4; ++r)
                pw[rr * 40 + smt * 16 + q4 * 4 + r] = f2bf(sacc[smt][r]);
        const bf16x8 pf = *(const bf16x8*)&pw[rr * 40 + q4 * 8];

        // O rescale only when some row-max moved (wave-uniform skip)
        if (__any(upd)) {
#pragma unroll
            for (int dt = 0; dt < 16; ++dt)
#pragma unroll
                for (int r = 0; r < 4; ++r) oacc[dt][r] *= alpha;
        }

        asm volatile("s_waitcnt vmcnt(4)" ::: "memory");   // V(c) landed; K(c+1) stays in flight
        __builtin_amdgcn_s_barrier();                      // all waves: V(c) visible

        // O^T += V^T P
#pragma unroll
        for (int dt = 0; dt < 16; ++dt) {
            bf16x8 vf = *(const bf16x8*)&Vs[(dt * 64 + lane) * 8];
            oacc[dt] = __builtin_amdgcn_mfma_f32_16x16x32_bf16(vf, pf, oacc[dt], 0, 0, 0);
        }
        __builtin_amdgcn_s_barrier();   // PV reads done before next STGV overwrite
    }
#undef STGK
#undef STGV

    // epilogue: lane holds (d = dt*16 + q4*4 + r, q = rr); pack r-pairs
    const float inv_l = 1.0f / fmaxf(l_, 1e-30f);
    const int t = blockIdx.x * 64 + wave * 16 + rr;
    unsigned short* orow = Ob + (size_t)(t * B_SZ + b) * F_DIM + h * DH;
#pragma unroll
    for (int dt = 0; dt < 16; ++dt) {
#pragma unroll
        for (int rp = 0; rp < 2; ++rp) {
            const unsigned int w = pkbf(oacc[dt][rp * 2] * inv_l,
                                        oacc[dt][rp * 2 + 1] * inv_l);
            *(unsigned int*)(orow + dt * 16 + q4 * 4 + rp * 2) = w;
        }
    }
}

// ---------------------------------------------------------------------------
extern "C" void kernel_launch(void* const* d_in, const int* in_sizes, int n_in,
                              void* d_out, int out_size, void* d_ws, size_t ws_size,
                              hipStream_t stream)
{
    const float* x  = (const float*)d_in[0];
    const float* Wq = (const float*)d_in[1];
    const float* bq = (const float*)d_in[2];
    const float* Wk = (const float*)d_in[3];
    const float* bk = (const float*)d_in[4];
    const float* Wv = (const float*)d_in[5];
    const float* bv = (const float*)d_in[6];
    const float* Wo = (const float*)d_in[7];
    const float* bo = (const float*)d_in[8];
    float* out = (float*)d_out;

    const int M = T_SEQ * B_SZ;   // 16384

    // workspace: Qf | Kb | Vb | Ob(=x_bf16 before attn) | Wpack | bqkv
    unsigned short* Qf = (unsigned short*)d_ws;
    unsigned short* Kb = Qf + (size_t)E_ELE;
    unsigned short* Vb = Kb + (size_t)E_ELE;
    unsigned short* Ob = Vb + (size_t)E_ELE;      // aliases x_bf16 (dead by attn)
    unsigned short* Wp = Ob + (size_t)E_ELE;      // [Wq;Wk;Wv;Wo] bf16
    float* bqkv = (float*)(Wp + (size_t)4 * W_ELE);
    unsigned short* xb = Ob;

    cvt_bf16<<<2048, 256, 0, stream>>>(x, xb, E_ELE / 8);
    cvt_w<<<dim3(W_ELE / 8 / 256, 4), 256, 0, stream>>>(Wq, Wk, Wv, Wo, bq, bk, bv, Wp, bqkv);

    // fused QKV: N = 3*768, writes Qf/Kb/Vb in fragment layouts
    gemm_nt<5><<<dim3(3 * F_DIM / 128, M / 128), 256, 0, stream>>>(
        xb, Wp, bqkv, Qf, M, 3 * F_DIM, F_DIM, 0.125f);

    attn_kernel<<<dim3(T_SEQ / 64, B_SZ * H_CNT), dim3(256), 0, stream>>>(Qf, Kb, Vb, Ob);

    gemm_nt<2><<<dim3(F_DIM / 128, M / 128), 256, 0, stream>>>(
        Ob, Wp + (size_t)3 * W_ELE, bo, out, M, F_DIM, F_DIM, 1.0f);
}

// Round 9
// 392.791 us; speedup vs baseline: 1.1178x; 1.1178x over previous
//
#include <hip/hip_runtime.h>
#include <cstdint>
#include <cstddef>

#define T_SEQ 2048
#define B_SZ  8
#define F_DIM 768
#define H_CNT 3
#define DH    256
#define E_ELE (T_SEQ * B_SZ * F_DIM)   // 12582912 elems per activation tensor
#define W_ELE (F_DIM * F_DIM)          // 589824 elems per weight matrix

typedef float floatx4 __attribute__((ext_vector_type(4)));
typedef short bf16x8  __attribute__((ext_vector_type(8)));

// round-half-up f32->bf16 (2 VALU); ties differ from RNE by 1 ulp (noise here)
static __device__ __forceinline__ unsigned short f2bf(float f) {
    union { float f; unsigned int i; } x; x.f = f;
    return (unsigned short)((x.i + 0x8000u) >> 16);
}
// pack two f32 -> u32 of two bf16 (lo=a, hi=b): 2 adds + v_perm
static __device__ __forceinline__ unsigned int pkbf(float a, float b) {
    union { float f; unsigned int i; } xa, xb; xa.f = a; xb.f = b;
    return __builtin_amdgcn_perm(xb.i + 0x8000u, xa.i + 0x8000u, 0x07060302u);
}
// load 8 consecutive fp32, convert to bf16x8 (packed converts)
static __device__ __forceinline__ bf16x8 cvt8(const float* __restrict__ p) {
    const floatx4 a = *(const floatx4*)p;
    const floatx4 b = *(const floatx4*)(p + 4);
    union { unsigned int u[4]; bf16x8 v; } r;
    r.u[0] = pkbf(a[0], a[1]); r.u[1] = pkbf(a[2], a[3]);
    r.u[2] = pkbf(b[0], b[1]); r.u[3] = pkbf(b[2], b[3]);
    return r.v;
}

// async global->LDS, 16B per lane; LDS dest = wave-uniform base + lane*16
#define ASYNC16(g, l) __builtin_amdgcn_global_load_lds( \
    (__attribute__((address_space(1))) void*)(void*)(g), \
    (__attribute__((address_space(3))) void*)(l), 16, 0, 0)

// ---------------------------------------------------------------------------
// Bulk fp32 -> bf16 (grid-stride over 8-elem chunks)
// ---------------------------------------------------------------------------
__global__ __launch_bounds__(256) void cvt_bf16(const float* __restrict__ src,
                                                unsigned short* __restrict__ dst,
                                                int n8)
{
    for (int i = blockIdx.x * 256 + threadIdx.x; i < n8; i += gridDim.x * 256)
        *(bf16x8*)(dst + (size_t)i * 8) = cvt8(src + (size_t)i * 8);
}

// Pack Wq|Wk|Wv|Wo -> bf16 [4*768][768]; pack bq|bk|bv -> fp32[2304].
__global__ __launch_bounds__(256) void cvt_w(
    const float* __restrict__ wq, const float* __restrict__ wk,
    const float* __restrict__ wv, const float* __restrict__ wo,
    const float* __restrict__ bq, const float* __restrict__ bk,
    const float* __restrict__ bv,
    unsigned short* __restrict__ wdst, float* __restrict__ bdst)
{
    const int y = blockIdx.y;
    const float* s = (y == 0) ? wq : (y == 1) ? wk : (y == 2) ? wv : wo;
    const int i = blockIdx.x * 256 + threadIdx.x;
    *(bf16x8*)(wdst + (size_t)y * W_ELE + (size_t)i * 8) = cvt8(s + (size_t)i * 8);
    if (y < 3 && i < F_DIM / 8) {
        const float* bs = (y == 0) ? bq : (y == 1) ? bk : bv;
        *(floatx4*)(bdst + y * F_DIM + i * 8)     = *(const floatx4*)(bs + i * 8);
        *(floatx4*)(bdst + y * F_DIM + i * 8 + 4) = *(const floatx4*)(bs + i * 8 + 4);
    }
}

// ---------------------------------------------------------------------------
// NT GEMM, BK=32, TRIPLE-buffered global_load_lds pipeline: stage(kt+2) is
// issued 2 iterations ahead, so vmcnt(4) at iteration kt waits on loads that
// have had ~2 compute phases (~600cyc) to land -> per-tile drain ~0 instead
// of ~500cyc (R2's 2-phase failed on coverage: 1 phase = 240cyc < latency).
// LDS 48KB -> still 3 blocks/CU. Order per iter: vmcnt(4) -> barrier ->
// stage(kt+2) (targets buf (kt-1)%3 whose reads retired at the barrier) ->
// compute(kt). Tail: dead-stages with clamped source keep vmcnt uniform.
// C = (A[M,K] * W[N,K]^T + bias) [* scale].
// CMODE 2: C fp32 row-major.  CMODE 5: fused QKV fragment-layout scatter.
// ---------------------------------------------------------------------------
template<int CMODE>
__global__ __launch_bounds__(256, 3) void gemm_nt(
    const unsigned short* __restrict__ A,
    const unsigned short* __restrict__ W,
    const float* __restrict__ bias,
    void* __restrict__ Cv,
    int M, int N, int K, float qscale)
{
    __shared__ __align__(16) unsigned short As[3][128 * 32];
    __shared__ __align__(16) unsigned short Bs[3][128 * 32];

    const int tid  = threadIdx.x;
    const int wave = tid >> 6;
    const int lane = tid & 63;
    const int m0 = blockIdx.y * 128;
    const int n0 = blockIdx.x * 128;
    const int wm = (wave >> 1) * 64;
    const int wn = (wave & 1) * 64;
    const int q4 = lane >> 4;
    const int rr = lane & 15;

    const int lrow = lane >> 2;        // row within 16-row chunk
    const int lk8  = (lane & 3) * 8;   // k-element offset
    const int ar0 = wave * 16 + lrow;
    const int ar1 = (wave + 4) * 16 + lrow;

    floatx4 acc[4][4];
#pragma unroll
    for (int i = 0; i < 4; ++i)
#pragma unroll
        for (int j = 0; j < 4; ++j) acc[i][j] = (floatx4)0.0f;

// stage k-offset kk_ into buffer bf_ (4 loads/wave: vmcnt +4)
#define STG(bf_, kk_) do { \
    ASYNC16(A + (size_t)(m0 + ar0) * K + (kk_) + lk8, (unsigned short*)As[bf_] + wave * 512); \
    ASYNC16(A + (size_t)(m0 + ar1) * K + (kk_) + lk8, (unsigned short*)As[bf_] + (wave + 4) * 512); \
    ASYNC16(W + (size_t)(n0 + ar0) * K + (kk_) + lk8, (unsigned short*)Bs[bf_] + wave * 512); \
    ASYNC16(W + (size_t)(n0 + ar1) * K + (kk_) + lk8, (unsigned short*)Bs[bf_] + (wave + 4) * 512); \
} while (0)

    const int KT = K >> 5;   // 24

    // prologue: k-tiles 0,1 in flight (outstanding = 8 loads/wave)
    STG(0, 0);
    STG(1, 32);

    for (int kt = 0; kt < KT; ++kt) {
        // k-tile kt (issued 2 iters ago) landed for this wave...
        asm volatile("s_waitcnt vmcnt(4)" ::: "memory");
        // ...and for all waves; also retires compute(kt-1)'s ds_reads
        __builtin_amdgcn_s_barrier();

        // issue kt+2 (dead-stage with clamped source past the end; keeps
        // outstanding count uniform at 8 after issue)
        const int k2 = (kt + 2 < KT) ? (kt + 2) * 32 : 0;
        STG((kt + 2) % 3, k2);

        const unsigned short* Ac = As[kt % 3];
        const unsigned short* Bc = Bs[kt % 3];
        bf16x8 af[4], bfv[4];
#pragma unroll
        for (int mt = 0; mt < 4; ++mt)
            af[mt] = *(const bf16x8*)&Ac[(wm + mt * 16 + rr) * 32 + q4 * 8];
#pragma unroll
        for (int nt = 0; nt < 4; ++nt)
            bfv[nt] = *(const bf16x8*)&Bc[(wn + nt * 16 + rr) * 32 + q4 * 8];
#pragma unroll
        for (int mt = 0; mt < 4; ++mt)
#pragma unroll
            for (int nt = 0; nt < 4; ++nt)
                acc[mt][nt] = __builtin_amdgcn_mfma_f32_16x16x32_bf16(af[mt], bfv[nt], acc[mt][nt], 0, 0, 0);
    }
#undef STG

#pragma unroll
    for (int nt = 0; nt < 4; ++nt) {
        const int col = n0 + wn + nt * 16 + rr;
        const float bv = bias[col];
        if (CMODE == 2) {
            float* C = (float*)Cv;
#pragma unroll
            for (int mt = 0; mt < 4; ++mt)
#pragma unroll
                for (int r = 0; r < 4; ++r) {
                    const int row = m0 + wm + mt * 16 + q4 * 4 + r;
                    C[(size_t)row * N + col] = acc[mt][nt][r] + bv;
                }
        } else {  // CMODE 5: fused QKV scatter (16-wide fragment layouts)
            const int mat = col / 768;           // wave-uniform per nt
            const int cl  = col - mat * 768;
            const int h = cl >> 8, d = cl & 255;
            const float sc = (mat == 0) ? qscale : 1.0f;
            unsigned short* base = (unsigned short*)Cv + (size_t)mat * E_ELE;
#pragma unroll
            for (int mt = 0; mt < 4; ++mt) {
#pragma unroll
                for (int r = 0; r < 4; ++r) {
                    const int row = m0 + wm + mt * 16 + q4 * 4 + r;
                    const float v = (acc[mt][nt][r] + bv) * sc;
                    const int t = row >> 3, bb = row & 7;   // row = t*B + b
                    const size_t hb = (size_t)(bb * H_CNT + h) * (T_SEQ * DH);
                    size_t idx;
                    if (mat < 2) {   // Q/K fragment layout
                        const int sblk = t >> 4, rrq = t & 15;
                        const int kc = d >> 5, q4v = (d >> 3) & 3, e = d & 7;
                        idx = hb + (size_t)(((sblk * 8 + kc) * 64 + q4v * 16 + rrq) * 8 + e);
                    } else {         // V fragment layout
                        const int skc = t >> 5, q4v = (t >> 3) & 3, e = t & 7;
                        const int dblk = d >> 4, rrq = d & 15;
                        idx = hb + (size_t)(((skc * 16 + dblk) * 64 + q4v * 16 + rrq) * 8 + e);
                    }
                    base[idx] = f2bf(v);
                }
            }
        }
    }
}

// ---------------------------------------------------------------------------
// Flash attention (R6 exact, measured best 157us): grid (T/64, B*H), 256
// threads (4 waves), 16 Q rows/wave. Scores transposed (S^T = K Q^T);
// softmax in-reg + 2 shuffles; K/V staged via global_load_lds w16.
// FROZEN: reg-staging (R2), 2x rows (R3), 32x32 (R4), no-LDS (R5), counted
// vmcnt dbuf (R8) all regressed. 4 blocks/CU wave supply is the load-hider.
// ---------------------------------------------------------------------------
__global__ __launch_bounds__(256, 3) void attn_kernel(
    const unsigned short* __restrict__ Qf,
    const unsigned short* __restrict__ Kf,
    const unsigned short* __restrict__ Vf,
    unsigned short* __restrict__ Ob)
{
    __shared__ __align__(16) unsigned short Ks[8192];       // [sblk2][kc8][64][8]
    __shared__ __align__(16) unsigned short Vs[8192];       // [dblk16][64][8]
    __shared__ __align__(16) unsigned short Ps[4][16 * 40]; // per-wave P[q][s], pad 8

    const int tid  = threadIdx.x;
    const int wave = tid >> 6;
    const int lane = tid & 63;
    const int q4 = lane >> 4;
    const int rr = lane & 15;
    const int bh = blockIdx.y;
    const int b  = bh / H_CNT;
    const int h  = bh % H_CNT;
    const size_t hb = (size_t)bh * (T_SEQ * DH);

    // wave's 16 Q rows = fragment tile sb (Q prescaled by 1/8 in the GEMM)
    const int sb = blockIdx.x * 4 + wave;
    bf16x8 qf_[8];
#pragma unroll
    for (int kc = 0; kc < 8; ++kc)
        qf_[kc] = *(const bf16x8*)(Qf + hb + ((size_t)(sb * 8 + kc) * 64 + lane) * 8);

    float m_ = -1e9f, l_ = 0.0f;
    floatx4 oacc[16];
#pragma unroll
    for (int dt = 0; dt < 16; ++dt) oacc[dt] = (floatx4)0.0f;

    const int so = wave * 2048 + lane * 8;   // staging src offset (elems)
    const int sd = wave * 2048;              // staging LDS base (elems)

    for (int s0 = 0; s0 < T_SEQ; s0 += 32) {
        const unsigned short* kg = Kf + hb + (size_t)(s0 >> 4) * 4096;
        const unsigned short* vg = Vf + hb + (size_t)(s0 >> 5) * 8192;
#pragma unroll
        for (int rnd = 0; rnd < 4; ++rnd) {
            ASYNC16(kg + so + rnd * 512, (unsigned short*)Ks + sd + rnd * 512);
            ASYNC16(vg + so + rnd * 512, (unsigned short*)Vs + sd + rnd * 512);
        }
        __syncthreads();   // vmcnt drain: tiles valid

        // S^T = K Q^T : D[s][q], s-tiles smt=0,1
        floatx4 sacc[2];
        sacc[0] = (floatx4)0.0f; sacc[1] = (floatx4)0.0f;
#pragma unroll
        for (int kc = 0; kc < 8; ++kc) {
            bf16x8 k0 = *(const bf16x8*)&Ks[(kc * 64 + lane) * 8];
            bf16x8 k1 = *(const bf16x8*)&Ks[((8 + kc) * 64 + lane) * 8];
            sacc[0] = __builtin_amdgcn_mfma_f32_16x16x32_bf16(k0, qf_[kc], sacc[0], 0, 0, 0);
            sacc[1] = __builtin_amdgcn_mfma_f32_16x16x32_bf16(k1, qf_[kc], sacc[1], 0, 0, 0);
        }

        // online softmax: lane's q-col = rr; 8 s-values in regs (smt, r)
        float cm = sacc[0][0];
#pragma unroll
        for (int smt = 0; smt < 2; ++smt)
#pragma unroll
            for (int r = 0; r < 4; ++r) cm = fmaxf(cm, sacc[smt][r]);
        cm = fmaxf(cm, __shfl_xor(cm, 16));
        cm = fmaxf(cm, __shfl_xor(cm, 32));
        const float mn = fmaxf(m_, cm);
        const float alpha = __expf(m_ - mn);
        float rs = 0.0f;
#pragma unroll
        for (int smt = 0; smt < 2; ++smt)
#pragma unroll
            for (int r = 0; r < 4; ++r) {
                const float p = __expf(sacc[smt][r] - mn);
                sacc[smt][r] = p; rs += p;
            }
        rs += __shfl_xor(rs, 16);
        rs += __shfl_xor(rs, 32);
        l_ = alpha * l_ + rs;
        const int upd = (mn > m_);
        m_ = mn;

        // P (S^T C-layout) -> per-wave LDS tile P[q][s] (stride 40)
        unsigned short* pw = Ps[wave];
#pragma unroll
        for (int smt = 0; smt < 2; ++smt)
#pragma unroll
            for (int r = 0; r < 4; ++r)
                pw[rr * 40 + smt * 16 + q4 * 4 + r] = f2bf(sacc[smt][r]);
        const bf16x8 pf = *(const bf16x8*)&pw[rr * 40 + q4 * 8];

        // O rescale only when some row-max moved (wave-uniform skip)
        if (__any(upd)) {
#pragma unroll
            for (int dt = 0; dt < 16; ++dt)
#pragma unroll
                for (int r = 0; r < 4; ++r) oacc[dt][r] *= alpha;
        }

        // O^T += V^T P
#pragma unroll
        for (int dt = 0; dt < 16; ++dt) {
            bf16x8 vf = *(const bf16x8*)&Vs[(dt * 64 + lane) * 8];
            oacc[dt] = __builtin_amdgcn_mfma_f32_16x16x32_bf16(vf, pf, oacc[dt], 0, 0, 0);
        }
        __syncthreads();   // tile reads done before next chunk's staging
    }

    // epilogue: lane holds (d = dt*16 + q4*4 + r, q = rr); pack r-pairs
    const float inv_l = 1.0f / fmaxf(l_, 1e-30f);
    const int t = blockIdx.x * 64 + wave * 16 + rr;
    unsigned short* orow = Ob + (size_t)(t * B_SZ + b) * F_DIM + h * DH;
#pragma unroll
    for (int dt = 0; dt < 16; ++dt) {
#pragma unroll
        for (int rp = 0; rp < 2; ++rp) {
            const unsigned int w = pkbf(oacc[dt][rp * 2] * inv_l,
                                        oacc[dt][rp * 2 + 1] * inv_l);
            *(unsigned int*)(orow + dt * 16 + q4 * 4 + rp * 2) = w;
        }
    }
}

// ---------------------------------------------------------------------------
extern "C" void kernel_launch(void* const* d_in, const int* in_sizes, int n_in,
                              void* d_out, int out_size, void* d_ws, size_t ws_size,
                              hipStream_t stream)
{
    const float* x  = (const float*)d_in[0];
    const float* Wq = (const float*)d_in[1];
    const float* bq = (const float*)d_in[2];
    const float* Wk = (const float*)d_in[3];
    const float* bk = (const float*)d_in[4];
    const float* Wv = (const float*)d_in[5];
    const float* bv = (const float*)d_in[6];
    const float* Wo = (const float*)d_in[7];
    const float* bo = (const float*)d_in[8];
    float* out = (float*)d_out;

    const int M = T_SEQ * B_SZ;   // 16384

    // workspace: Qf | Kb | Vb | Ob(=x_bf16 before attn) | Wpack | bqkv
    unsigned short* Qf = (unsigned short*)d_ws;
    unsigned short* Kb = Qf + (size_t)E_ELE;
    unsigned short* Vb = Kb + (size_t)E_ELE;
    unsigned short* Ob = Vb + (size_t)E_ELE;      // aliases x_bf16 (dead by attn)
    unsigned short* Wp = Ob + (size_t)E_ELE;      // [Wq;Wk;Wv;Wo] bf16
    float* bqkv = (float*)(Wp + (size_t)4 * W_ELE);
    unsigned short* xb = Ob;

    cvt_bf16<<<2048, 256, 0, stream>>>(x, xb, E_ELE / 8);
    cvt_w<<<dim3(W_ELE / 8 / 256, 4), 256, 0, stream>>>(Wq, Wk, Wv, Wo, bq, bk, bv, Wp, bqkv);

    // fused QKV: N = 3*768, writes Qf/Kb/Vb in fragment layouts
    gemm_nt<5><<<dim3(3 * F_DIM / 128, M / 128), 256, 0, stream>>>(
        xb, Wp, bqkv, Qf, M, 3 * F_DIM, F_DIM, 0.125f);

    attn_kernel<<<dim3(T_SEQ / 64, B_SZ * H_CNT), dim3(256), 0, stream>>>(Qf, Kb, Vb, Ob);

    gemm_nt<2><<<dim3(F_DIM / 128, M / 128), 256, 0, stream>>>(
        Ob, Wp + (size_t)3 * W_ELE, bo, out, M, F_DIM, F_DIM, 1.0f);
}

// Round 10
// 353.231 us; speedup vs baseline: 1.2430x; 1.1120x over previous
//
#include <hip/hip_runtime.h>
#include <cstdint>
#include <cstddef>

#define T_SEQ 2048
#define B_SZ  8
#define F_DIM 768
#define H_CNT 3
#define DH    256
#define E_ELE (T_SEQ * B_SZ * F_DIM)   // 12582912 elems per activation tensor
#define W_ELE (F_DIM * F_DIM)          // 589824 elems per weight matrix

typedef float floatx4 __attribute__((ext_vector_type(4)));
typedef short bf16x8  __attribute__((ext_vector_type(8)));

// round-half-up f32->bf16 (2 VALU); ties differ from RNE by 1 ulp (noise here)
static __device__ __forceinline__ unsigned short f2bf(float f) {
    union { float f; unsigned int i; } x; x.f = f;
    return (unsigned short)((x.i + 0x8000u) >> 16);
}
// pack two f32 -> u32 of two bf16 (lo=a, hi=b): 2 adds + v_perm
static __device__ __forceinline__ unsigned int pkbf(float a, float b) {
    union { float f; unsigned int i; } xa, xb; xa.f = a; xb.f = b;
    return __builtin_amdgcn_perm(xb.i + 0x8000u, xa.i + 0x8000u, 0x07060302u);
}
// load 8 consecutive fp32, convert to bf16x8 (packed converts)
static __device__ __forceinline__ bf16x8 cvt8(const float* __restrict__ p) {
    const floatx4 a = *(const floatx4*)p;
    const floatx4 b = *(const floatx4*)(p + 4);
    union { unsigned int u[4]; bf16x8 v; } r;
    r.u[0] = pkbf(a[0], a[1]); r.u[1] = pkbf(a[2], a[3]);
    r.u[2] = pkbf(b[0], b[1]); r.u[3] = pkbf(b[2], b[3]);
    return r.v;
}

// async global->LDS, 16B per lane; LDS dest = wave-uniform base + lane*16
#define ASYNC16(g, l) __builtin_amdgcn_global_load_lds( \
    (__attribute__((address_space(1))) void*)(void*)(g), \
    (__attribute__((address_space(3))) void*)(l), 16, 0, 0)

// ---------------------------------------------------------------------------
// Bulk fp32 -> bf16 (grid-stride over 8-elem chunks)
// ---------------------------------------------------------------------------
__global__ __launch_bounds__(256) void cvt_bf16(const float* __restrict__ src,
                                                unsigned short* __restrict__ dst,
                                                int n8)
{
    for (int i = blockIdx.x * 256 + threadIdx.x; i < n8; i += gridDim.x * 256)
        *(bf16x8*)(dst + (size_t)i * 8) = cvt8(src + (size_t)i * 8);
}

// Pack Wq|Wk|Wv|Wo -> bf16 [4*768][768]; pack bq|bk|bv -> fp32[2304].
__global__ __launch_bounds__(256) void cvt_w(
    const float* __restrict__ wq, const float* __restrict__ wk,
    const float* __restrict__ wv, const float* __restrict__ wo,
    const float* __restrict__ bq, const float* __restrict__ bk,
    const float* __restrict__ bv,
    unsigned short* __restrict__ wdst, float* __restrict__ bdst)
{
    const int y = blockIdx.y;
    const float* s = (y == 0) ? wq : (y == 1) ? wk : (y == 2) ? wv : wo;
    const int i = blockIdx.x * 256 + threadIdx.x;
    *(bf16x8*)(wdst + (size_t)y * W_ELE + (size_t)i * 8) = cvt8(s + (size_t)i * 8);
    if (y < 3 && i < F_DIM / 8) {
        const float* bs = (y == 0) ? bq : (y == 1) ? bk : bv;
        *(floatx4*)(bdst + y * F_DIM + i * 8)     = *(const floatx4*)(bs + i * 8);
        *(floatx4*)(bdst + y * F_DIM + i * 8 + 4) = *(const floatx4*)(bs + i * 8 + 4);
    }
}

// ---------------------------------------------------------------------------
// NT GEMM (R6 structure, measured best): both operands bf16, staged via
// global_load_lds w16, BK=64, single-buffer 2-barrier loop. Granule XOR
// swizzle: linear LDS dest + inverse-swizzled GLOBAL source + swizzled
// ds_read granule -> 2-way conflicts (free).
// R10 delta: __launch_bounds__(256,4) -- cap VGPR at 128 (live state ~120)
// so 4 blocks/CU co-reside instead of 3; inter-block overlap is the proven
// latency hider here (R2/R7/R9 in-block pipelines all null/regressed).
// C = (A[M,K] * W[N,K]^T + bias) [* scale].
// CMODE 2: C fp32 row-major.  CMODE 5: fused QKV fragment-layout scatter.
// ---------------------------------------------------------------------------
template<int CMODE>
__global__ __launch_bounds__(256, 4) void gemm_nt(
    const unsigned short* __restrict__ A,
    const unsigned short* __restrict__ W,
    const float* __restrict__ bias,
    void* __restrict__ Cv,
    int M, int N, int K, float qscale)
{
    __shared__ __align__(16) unsigned short As[128 * 64];
    __shared__ __align__(16) unsigned short Bs[128 * 64];

    const int tid  = threadIdx.x;
    const int wave = tid >> 6;
    const int lane = tid & 63;
    const int m0 = blockIdx.y * 128;
    const int n0 = blockIdx.x * 128;
    const int wm = (wave >> 1) * 64;
    const int wn = (wave & 1) * 64;
    const int q4 = lane >> 4;
    const int rr = lane & 15;

    // staging geometry: per ASYNC16 call a wave covers 8 rows x 64 elems.
    const int srow = lane >> 3;                 // row within 8-row group
    const int scol = ((lane & 7) ^ srow) * 8;   // inverse-swizzled src granule

    floatx4 acc[4][4];
#pragma unroll
    for (int i = 0; i < 4; ++i)
#pragma unroll
        for (int j = 0; j < 4; ++j) acc[i][j] = (floatx4)0.0f;

    for (int k0 = 0; k0 < K; k0 += 64) {
        __syncthreads();   // previous iteration's fragment reads complete
#pragma unroll
        for (int c = 0; c < 4; ++c) {
            const int g = wave * 4 + c;         // rowgroup 0..15
            ASYNC16(A + (size_t)(m0 + g * 8 + srow) * K + k0 + scol,
                    (unsigned short*)As + g * 512);
            ASYNC16(W + (size_t)(n0 + g * 8 + srow) * K + k0 + scol,
                    (unsigned short*)Bs + g * 512);
        }
        __syncthreads();   // staging visible (drains vmcnt)

#pragma unroll
        for (int kh = 0; kh < 2; ++kh) {
            bf16x8 af[4], bfv[4];
#pragma unroll
            for (int mt = 0; mt < 4; ++mt) {
                const int row = wm + mt * 16 + rr;
                const int pg = (kh * 4 + q4) ^ (rr & 7);   // swizzled granule
                af[mt] = *(const bf16x8*)&As[row * 64 + pg * 8];
            }
#pragma unroll
            for (int nt = 0; nt < 4; ++nt) {
                const int row = wn + nt * 16 + rr;
                const int pg = (kh * 4 + q4) ^ (rr & 7);
                bfv[nt] = *(const bf16x8*)&Bs[row * 64 + pg * 8];
            }
#pragma unroll
            for (int mt = 0; mt < 4; ++mt)
#pragma unroll
                for (int nt = 0; nt < 4; ++nt)
                    acc[mt][nt] = __builtin_amdgcn_mfma_f32_16x16x32_bf16(af[mt], bfv[nt], acc[mt][nt], 0, 0, 0);
        }
    }

#pragma unroll
    for (int nt = 0; nt < 4; ++nt) {
        const int col = n0 + wn + nt * 16 + rr;
        const float bv = bias[col];
        if (CMODE == 2) {
            float* C = (float*)Cv;
#pragma unroll
            for (int mt = 0; mt < 4; ++mt)
#pragma unroll
                for (int r = 0; r < 4; ++r) {
                    const int row = m0 + wm + mt * 16 + q4 * 4 + r;
                    C[(size_t)row * N + col] = acc[mt][nt][r] + bv;
                }
        } else {  // CMODE 5: fused QKV scatter (16-wide fragment layouts)
            const int mat = col / 768;           // wave-uniform per nt
            const int cl  = col - mat * 768;
            const int h = cl >> 8, d = cl & 255;
            const float sc = (mat == 0) ? qscale : 1.0f;
            unsigned short* base = (unsigned short*)Cv + (size_t)mat * E_ELE;
#pragma unroll
            for (int mt = 0; mt < 4; ++mt) {
#pragma unroll
                for (int r = 0; r < 4; ++r) {
                    const int row = m0 + wm + mt * 16 + q4 * 4 + r;
                    const float v = (acc[mt][nt][r] + bv) * sc;
                    const int t = row >> 3, bb = row & 7;   // row = t*B + b
                    const size_t hb = (size_t)(bb * H_CNT + h) * (T_SEQ * DH);
                    size_t idx;
                    if (mat < 2) {   // Q/K fragment layout
                        const int sblk = t >> 4, rrq = t & 15;
                        const int kc = d >> 5, q4v = (d >> 3) & 3, e = d & 7;
                        idx = hb + (size_t)(((sblk * 8 + kc) * 64 + q4v * 16 + rrq) * 8 + e);
                    } else {         // V fragment layout
                        const int skc = t >> 5, q4v = (t >> 3) & 3, e = t & 7;
                        const int dblk = d >> 4, rrq = d & 15;
                        idx = hb + (size_t)(((skc * 16 + dblk) * 64 + q4v * 16 + rrq) * 8 + e);
                    }
                    base[idx] = f2bf(v);
                }
            }
        }
    }
}

// ---------------------------------------------------------------------------
// Flash attention (R6 structure, measured best 157us): grid (T/64, B*H), 256
// threads (4 waves), 16 Q rows/wave. Scores transposed (S^T = K Q^T);
// softmax in-reg + 2 shuffles; K/V staged via global_load_lds w16.
// FROZEN structure: reg-staging (R2), 2x rows (R3), 32x32 (R4), no-LDS (R5),
// counted-vmcnt dbuf (R8) all regressed. R10 delta: s_setprio around the two
// MFMA clusters (T5, measured +4-7% on attn-class kernels).
// ---------------------------------------------------------------------------
__global__ __launch_bounds__(256, 3) void attn_kernel(
    const unsigned short* __restrict__ Qf,
    const unsigned short* __restrict__ Kf,
    const unsigned short* __restrict__ Vf,
    unsigned short* __restrict__ Ob)
{
    __shared__ __align__(16) unsigned short Ks[8192];       // [sblk2][kc8][64][8]
    __shared__ __align__(16) unsigned short Vs[8192];       // [dblk16][64][8]
    __shared__ __align__(16) unsigned short Ps[4][16 * 40]; // per-wave P[q][s], pad 8

    const int tid  = threadIdx.x;
    const int wave = tid >> 6;
    const int lane = tid & 63;
    const int q4 = lane >> 4;
    const int rr = lane & 15;
    const int bh = blockIdx.y;
    const int b  = bh / H_CNT;
    const int h  = bh % H_CNT;
    const size_t hb = (size_t)bh * (T_SEQ * DH);

    // wave's 16 Q rows = fragment tile sb (Q prescaled by 1/8 in the GEMM)
    const int sb = blockIdx.x * 4 + wave;
    bf16x8 qf_[8];
#pragma unroll
    for (int kc = 0; kc < 8; ++kc)
        qf_[kc] = *(const bf16x8*)(Qf + hb + ((size_t)(sb * 8 + kc) * 64 + lane) * 8);

    float m_ = -1e9f, l_ = 0.0f;
    floatx4 oacc[16];
#pragma unroll
    for (int dt = 0; dt < 16; ++dt) oacc[dt] = (floatx4)0.0f;

    const int so = wave * 2048 + lane * 8;   // staging src offset (elems)
    const int sd = wave * 2048;              // staging LDS base (elems)

    for (int s0 = 0; s0 < T_SEQ; s0 += 32) {
        const unsigned short* kg = Kf + hb + (size_t)(s0 >> 4) * 4096;
        const unsigned short* vg = Vf + hb + (size_t)(s0 >> 5) * 8192;
#pragma unroll
        for (int rnd = 0; rnd < 4; ++rnd) {
            ASYNC16(kg + so + rnd * 512, (unsigned short*)Ks + sd + rnd * 512);
            ASYNC16(vg + so + rnd * 512, (unsigned short*)Vs + sd + rnd * 512);
        }
        __syncthreads();   // vmcnt drain: tiles valid

        // S^T = K Q^T : D[s][q], s-tiles smt=0,1
        floatx4 sacc[2];
        sacc[0] = (floatx4)0.0f; sacc[1] = (floatx4)0.0f;
        __builtin_amdgcn_s_setprio(1);
#pragma unroll
        for (int kc = 0; kc < 8; ++kc) {
            bf16x8 k0 = *(const bf16x8*)&Ks[(kc * 64 + lane) * 8];
            bf16x8 k1 = *(const bf16x8*)&Ks[((8 + kc) * 64 + lane) * 8];
            sacc[0] = __builtin_amdgcn_mfma_f32_16x16x32_bf16(k0, qf_[kc], sacc[0], 0, 0, 0);
            sacc[1] = __builtin_amdgcn_mfma_f32_16x16x32_bf16(k1, qf_[kc], sacc[1], 0, 0, 0);
        }
        __builtin_amdgcn_s_setprio(0);

        // online softmax: lane's q-col = rr; 8 s-values in regs (smt, r)
        float cm = sacc[0][0];
#pragma unroll
        for (int smt = 0; smt < 2; ++smt)
#pragma unroll
            for (int r = 0; r < 4; ++r) cm = fmaxf(cm, sacc[smt][r]);
        cm = fmaxf(cm, __shfl_xor(cm, 16));
        cm = fmaxf(cm, __shfl_xor(cm, 32));
        const float mn = fmaxf(m_, cm);
        const float alpha = __expf(m_ - mn);
        float rs = 0.0f;
#pragma unroll
        for (int smt = 0; smt < 2; ++smt)
#pragma unroll
            for (int r = 0; r < 4; ++r) {
                const float p = __expf(sacc[smt][r] - mn);
                sacc[smt][r] = p; rs += p;
            }
        rs += __shfl_xor(rs, 16);
        rs += __shfl_xor(rs, 32);
        l_ = alpha * l_ + rs;
        const int upd = (mn > m_);
        m_ = mn;

        // P (S^T C-layout) -> per-wave LDS tile P[q][s] (stride 40)
        unsigned short* pw = Ps[wave];
#pragma unroll
        for (int smt = 0; smt < 2; ++smt)
#pragma unroll
            for (int r = 0; r < 4; ++r)
                pw[rr * 40 + smt * 16 + q4 * 4 + r] = f2bf(sacc[smt][r]);
        const bf16x8 pf = *(const bf16x8*)&pw[rr * 40 + q4 * 8];

        // O rescale only when some row-max moved (wave-uniform skip)
        if (__any(upd)) {
#pragma unroll
            for (int dt = 0; dt < 16; ++dt)
#pragma unroll
                for (int r = 0; r < 4; ++r) oacc[dt][r] *= alpha;
        }

        // O^T += V^T P
        __builtin_amdgcn_s_setprio(1);
#pragma unroll
        for (int dt = 0; dt < 16; ++dt) {
            bf16x8 vf = *(const bf16x8*)&Vs[(dt * 64 + lane) * 8];
            oacc[dt] = __builtin_amdgcn_mfma_f32_16x16x32_bf16(vf, pf, oacc[dt], 0, 0, 0);
        }
        __builtin_amdgcn_s_setprio(0);
        __syncthreads();   // tile reads done before next chunk's staging
    }

    // epilogue: lane holds (d = dt*16 + q4*4 + r, q = rr); pack r-pairs
    const float inv_l = 1.0f / fmaxf(l_, 1e-30f);
    const int t = blockIdx.x * 64 + wave * 16 + rr;
    unsigned short* orow = Ob + (size_t)(t * B_SZ + b) * F_DIM + h * DH;
#pragma unroll
    for (int dt = 0; dt < 16; ++dt) {
#pragma unroll
        for (int rp = 0; rp < 2; ++rp) {
            const unsigned int w = pkbf(oacc[dt][rp * 2] * inv_l,
                                        oacc[dt][rp * 2 + 1] * inv_l);
            *(unsigned int*)(orow + dt * 16 + q4 * 4 + rp * 2) = w;
        }
    }
}

// ---------------------------------------------------------------------------
extern "C" void kernel_launch(void* const* d_in, const int* in_sizes, int n_in,
                              void* d_out, int out_size, void* d_ws, size_t ws_size,
                              hipStream_t stream)
{
    const float* x  = (const float*)d_in[0];
    const float* Wq = (const float*)d_in[1];
    const float* bq = (const float*)d_in[2];
    const float* Wk = (const float*)d_in[3];
    const float* bk = (const float*)d_in[4];
    const float* Wv = (const float*)d_in[5];
    const float* bv = (const float*)d_in[6];
    const float* Wo = (const float*)d_in[7];
    const float* bo = (const float*)d_in[8];
    float* out = (float*)d_out;

    const int M = T_SEQ * B_SZ;   // 16384

    // workspace: Qf | Kb | Vb | Ob(=x_bf16 before attn) | Wpack | bqkv
    unsigned short* Qf = (unsigned short*)d_ws;
    unsigned short* Kb = Qf + (size_t)E_ELE;
    unsigned short* Vb = Kb + (size_t)E_ELE;
    unsigned short* Ob = Vb + (size_t)E_ELE;      // aliases x_bf16 (dead by attn)
    unsigned short* Wp = Ob + (size_t)E_ELE;      // [Wq;Wk;Wv;Wo] bf16
    float* bqkv = (float*)(Wp + (size_t)4 * W_ELE);
    unsigned short* xb = Ob;

    cvt_bf16<<<2048, 256, 0, stream>>>(x, xb, E_ELE / 8);
    cvt_w<<<dim3(W_ELE / 8 / 256, 4), 256, 0, stream>>>(Wq, Wk, Wv, Wo, bq, bk, bv, Wp, bqkv);

    // fused QKV: N = 3*768, writes Qf/Kb/Vb in fragment layouts
    gemm_nt<5><<<dim3(3 * F_DIM / 128, M / 128), 256, 0, stream>>>(
        xb, Wp, bqkv, Qf, M, 3 * F_DIM, F_DIM, 0.125f);

    attn_kernel<<<dim3(T_SEQ / 64, B_SZ * H_CNT), dim3(256), 0, stream>>>(Qf, Kb, Vb, Ob);

    gemm_nt<2><<<dim3(F_DIM / 128, M / 128), 256, 0, stream>>>(
        Ob, Wp + (size_t)3 * W_ELE, bo, out, M, F_DIM, F_DIM, 1.0f);
}